// Round 21
// baseline (389.015 us; speedup 1.0000x reference)
//
#include <hip/hip_runtime.h>
#include <hip/hip_fp16.h>

#define BQ 256
#define TQ 1024
#define FQ 37
#define UQ 64
#define G3 192
#define CH 8
#define NCK (TQ / CH)
#define CFD (CH * FQ)   // 296 dwords per staged chunk

typedef _Float16 h2v __attribute__((ext_vector_type(2)));

__device__ __forceinline__ float sigmoid_f(float x) {
    return 1.0f / (1.0f + __expf(-x));
}
__device__ __forceinline__ float tanh_f(float x) {
    return 1.0f - 2.0f / (__expf(2.0f * x) + 1.0f);
}
__device__ __forceinline__ float fdot2f(h2v a, h2v b, float c) {
#if __has_builtin(__builtin_amdgcn_fdot2)
    return __builtin_amdgcn_fdot2(a, b, c, false);
#else
    float d;
    asm("v_dot2_f32_f16 %0, %1, %2, %3" : "=v"(d) : "v"(a), "v"(b), "v"(c));
    return d;
#endif
}
__device__ __forceinline__ h2v u2h(unsigned int u) {
    union { unsigned int x; h2v h; } v; v.x = u; return v.h;
}

// R20 (381us) with the consumer's h-broadcast moved OFF the LDS write->read
// round-trip: h pairs are packed in-register (RTE cvt + mov_dpp quad_perm +
// bit-pack -> bit-identical h values to R20) and each step pulls all 32
// fp16-pairs via 32 INDEPENDENT uniform-index ds_bpermute_b32 (one pipelined
// ~100cy latency instead of write-lat + read-lat serially; no in-order-after-
// write dependency). The s_h16 ring write remains for the producer's HEAD but
// is fire-and-forget (nothing waits until the chunk-end barrier).
// Accumulation order unchanged -> absmax should stay exactly 0.00390625.
__global__ __launch_bounds__(128)
__attribute__((amdgpu_waves_per_eu(1, 1)))
void gru_fused(const float* __restrict__ values,   // [B,T,F]
               const int*   __restrict__ lengths,  // [B]
               const float* __restrict__ Wk,       // [F,3U]
               const float* __restrict__ Wr,       // [U,3U]
               const float* __restrict__ bias,     // [2,3U]
               const float* __restrict__ dw,       // [U]
               const float* __restrict__ db,       // [1]
               float*       __restrict__ out)      // [B,T]
{
    const int tid = threadIdx.x;
    const int j   = tid & 63;
    const int w   = tid >> 6;
    const int b   = blockIdx.x;

    __shared__ __align__(16) float    s_v[2][CH][40];     // staged values (dbuf)
    __shared__ __align__(16) float4   s_xp4[2][CH][64];   // packed xp {z,r,h,-}
    __shared__ __align__(16) _Float16 s_h16[2][CH][72];   // h ring (for HEAD)

    const float* vbp = values + (size_t)b * TQ * FQ;
    float* ob = out + (size_t)b * TQ;

    if (w == 0) {
        // ================= CONSUMER =================
        h2v Pz[32], Pr[32], Ph[32];          // fp16 weight pairs (96 VGPRs)
#pragma unroll
        for (int i = 0; i < 32; ++i) {
            h2v tz, tr, th;
            tz.x = (_Float16)Wr[(2 * i) * G3 + j];
            tz.y = (_Float16)Wr[(2 * i + 1) * G3 + j];
            tr.x = (_Float16)Wr[(2 * i) * G3 + 64 + j];
            tr.y = (_Float16)Wr[(2 * i + 1) * G3 + 64 + j];
            th.x = (_Float16)Wr[(2 * i) * G3 + 128 + j];
            th.y = (_Float16)Wr[(2 * i + 1) * G3 + 128 + j];
            Pz[i] = tz; Pr[i] = tr; Ph[i] = th;
        }
        const float bh  = bias[G3 + 128 + j];    // h-gate recurrent bias
        const int   len = lengths[b];

        __builtin_amdgcn_s_barrier();            // prologue barrier

        float h = 0.0f;                          // lane j holds h_j
        int hpk = 0;                             // packed {h_2i, h_2i+1} (even lanes)

#define CSTEP(TC, XQ)                                                         \
        {                                                                     \
            int hv_i[32];                                                     \
            _Pragma("unroll")                                                 \
            for (int p = 0; p < 32; ++p)                                      \
                hv_i[p] = __builtin_amdgcn_ds_bpermute(8 * p, hpk);           \
            float az0 = 0.f, az1 = 0.f, ar0 = 0.f, ar1 = 0.f,                 \
                  ah0 = 0.f, ah1 = 0.f;                                       \
            _Pragma("unroll")                                                 \
            for (int p = 0; p < 32; p += 2) {                                 \
                const h2v a = u2h((unsigned int)hv_i[p]);                     \
                const h2v c = u2h((unsigned int)hv_i[p + 1]);                 \
                az0 = fdot2f(Pz[p],     a, az0);                              \
                az1 = fdot2f(Pz[p + 1], c, az1);                              \
                ar0 = fdot2f(Pr[p],     a, ar0);                              \
                ar1 = fdot2f(Pr[p + 1], c, ar1);                              \
                ah0 = fdot2f(Ph[p],     a, ah0);                              \
                ah1 = fdot2f(Ph[p + 1], c, ah1);                              \
            }                                                                 \
            const float z  = sigmoid_f((XQ).x + (az0 + az1));                 \
            const float r  = sigmoid_f((XQ).y + (ar0 + ar1));                 \
            const float cc = tanh_f((XQ).z + r * (bh + (ah0 + ah1)));         \
            const float hn = z * h + (1.0f - z) * cc;                         \
            h = ((tbase + (TC)) < len) ? hn : h;                              \
            const unsigned int h16 =                                          \
                (unsigned int)__half_as_ushort(__float2half(h));  /* RTE */   \
            s_h16[pb][TC][j] = *(const _Float16*)&h16;   /* head ring */      \
            const unsigned int nb16 = (unsigned int)__builtin_amdgcn_mov_dpp( \
                (int)h16, 0xB1, 0xF, 0xF, true);  /* quad_perm [1,0,3,2] */   \
            hpk = (int)((nb16 << 16) | (h16 & 0xFFFFu));                      \
        }

#pragma unroll 1
        for (int k = 0; k < NCK; ++k) {
            const int pb = k & 1;
            const int tbase = k * CH;
            // all 8 steps' packed xp: issued up-front, latency hides
            const float4* xpr = &s_xp4[pb][0][j];
            float4 xq0 = xpr[0 * 64], xq1 = xpr[1 * 64];
            float4 xq2 = xpr[2 * 64], xq3 = xpr[3 * 64];
            float4 xq4 = xpr[4 * 64], xq5 = xpr[5 * 64];
            float4 xq6 = xpr[6 * 64], xq7 = xpr[7 * 64];
            CSTEP(0, xq0) CSTEP(1, xq1) CSTEP(2, xq2) CSTEP(3, xq3)
            CSTEP(4, xq4) CSTEP(5, xq5) CSTEP(6, xq6) CSTEP(7, xq7)
            asm volatile("s_waitcnt lgkmcnt(0)" ::: "memory");
            __builtin_amdgcn_s_barrier();        // once per 8 steps
        }
#undef CSTEP
    } else {
        // ================= PRODUCER (verbatim R20) =================
        float Kz[FQ], Kr[FQ], Kh[FQ];
#pragma unroll
        for (int f = 0; f < FQ; ++f) {
            Kz[f] = Wk[f * G3 + j];
            Kr[f] = Wk[f * G3 + 64 + j];
            Kh[f] = Wk[f * G3 + 128 + j];
        }
        const float bz  = bias[j] + bias[G3 + j];            // fold rec bias z
        const float br  = bias[64 + j] + bias[G3 + 64 + j];  // fold rec bias r
        const float bhx = bias[128 + j];                     // input bias only
        const float dbv = db[0];
        float dwv[8];
#pragma unroll
        for (int i = 0; i < 8; ++i) dwv[i] = dw[(j & 7) * 8 + i];

        int rq[5], cq[5];
        bool act[5];
        float stg[5];
#pragma unroll
        for (int q = 0; q < 5; ++q) {
            const int idx = j + 64 * q;
            act[q] = idx < CFD;
            rq[q] = idx / FQ;
            cq[q] = idx - rq[q] * FQ;
            stg[q] = 0.0f;
        }

#define STAGE_LOAD(CK)                                                        \
        _Pragma("unroll")                                                     \
        for (int q = 0; q < 5; ++q)                                           \
            if (act[q]) stg[q] = vbp[(size_t)(CK) * CFD + j + 64 * q];
#define STAGE_WRITE(SB)                                                       \
        _Pragma("unroll")                                                     \
        for (int q = 0; q < 5; ++q)                                           \
            if (act[q]) s_v[SB][rq[q]][cq[q]] = stg[q];

#define XF(VAL, I) { az += (VAL) * Kz[I]; ar += (VAL) * Kr[I]; ah += (VAL) * Kh[I]; }
#define XPROW(BB)                                                             \
    _Pragma("unroll 1")                                                       \
    for (int row = 0; row < CH; ++row) {                                      \
        const float4* vr = (const float4*)&s_v[BB][row][0];                   \
        float az = bz, ar = br, ah = bhx;                                     \
        { float4 v0 = vr[0], v1 = vr[1], v2 = vr[2];                          \
          XF(v0.x, 0)  XF(v0.y, 1)  XF(v0.z, 2)  XF(v0.w, 3)                  \
          XF(v1.x, 4)  XF(v1.y, 5)  XF(v1.z, 6)  XF(v1.w, 7)                  \
          XF(v2.x, 8)  XF(v2.y, 9)  XF(v2.z, 10) XF(v2.w, 11) }               \
        { float4 v3 = vr[3], v4 = vr[4], v5 = vr[5];                          \
          XF(v3.x, 12) XF(v3.y, 13) XF(v3.z, 14) XF(v3.w, 15)                 \
          XF(v4.x, 16) XF(v4.y, 17) XF(v4.z, 18) XF(v4.w, 19)                 \
          XF(v5.x, 20) XF(v5.y, 21) XF(v5.z, 22) XF(v5.w, 23) }               \
        { float4 v6 = vr[6], v7 = vr[7], v8 = vr[8];                          \
          float f36 = s_v[BB][row][36];                                       \
          XF(v6.x, 24) XF(v6.y, 25) XF(v6.z, 26) XF(v6.w, 27)                 \
          XF(v7.x, 28) XF(v7.y, 29) XF(v7.z, 30) XF(v7.w, 31)                 \
          XF(v8.x, 32) XF(v8.y, 33) XF(v8.z, 34) XF(v8.w, 35)                 \
          XF(f36, 36) }                                                       \
        float4 xo; xo.x = az; xo.y = ar; xo.z = ah; xo.w = 0.f;               \
        s_xp4[BB][row][j] = xo;                                               \
    }

#define HEAD(HB, TB)                                                          \
    {                                                                         \
        const int e = j & 7, s = j >> 3;                                      \
        float4 hw = *(const float4*)&s_h16[HB][s][e * 8];                     \
        const h2v* hp_ = (const h2v*)&hw;                                     \
        float pp = (float)hp_[0].x * dwv[0] + (float)hp_[0].y * dwv[1]        \
                 + (float)hp_[1].x * dwv[2] + (float)hp_[1].y * dwv[3]        \
                 + (float)hp_[2].x * dwv[4] + (float)hp_[2].y * dwv[5]        \
                 + (float)hp_[3].x * dwv[6] + (float)hp_[3].y * dwv[7];       \
        pp += __shfl_xor(pp, 1, 64);                                          \
        pp += __shfl_xor(pp, 2, 64);                                          \
        pp += __shfl_xor(pp, 4, 64);                                          \
        if (e == 0) ob[(TB) + s] = sigmoid_f(pp + dbv);                       \
    }

        // prologue: chunk0 -> s_v[0]; chunk1 -> s_v[1]; issue chunk2; xp(chunk0)
        STAGE_LOAD(0)
        asm volatile("s_waitcnt vmcnt(0)" ::: "memory");
        STAGE_WRITE(0)
        STAGE_LOAD(1)
        asm volatile("s_waitcnt vmcnt(0)" ::: "memory");
        STAGE_WRITE(1)
        STAGE_LOAD(2)
        asm volatile("s_waitcnt lgkmcnt(0)" ::: "memory");  // own s_v visible
        XPROW(0)
        asm volatile("s_waitcnt lgkmcnt(0)" ::: "memory");
        __builtin_amdgcn_s_barrier();            // prologue barrier

#pragma unroll 1
        for (int k = 0; k < NCK; ++k) {
            const int pb = k & 1, nb = pb ^ 1;
            if (k > 0) HEAD(nb, (k - 1) * CH)
            if (k + 2 < NCK) {
                asm volatile("s_waitcnt vmcnt(0)" ::: "memory");
                STAGE_WRITE(pb)                  // chunk k+2
                if (k + 3 < NCK) STAGE_LOAD(k + 3)
            }
            if (k + 1 < NCK) XPROW(nb)           // xp chunk k+1 from s_v[nb]
            asm volatile("s_waitcnt lgkmcnt(0)" ::: "memory");
            __builtin_amdgcn_s_barrier();        // once per 8 steps
        }
        HEAD((NCK - 1) & 1, (NCK - 1) * CH)      // after final barrier (R13 fix)

#undef STAGE_LOAD
#undef STAGE_WRITE
#undef XF
#undef XPROW
#undef HEAD
    }
}

extern "C" void kernel_launch(void* const* d_in, const int* in_sizes, int n_in,
                              void* d_out, int out_size, void* d_ws, size_t ws_size,
                              hipStream_t stream) {
    const float* values  = (const float*)d_in[2];
    const int*   lengths = (const int*)  d_in[4];
    const float* Wk      = (const float*)d_in[5];
    const float* Wr      = (const float*)d_in[6];
    const float* bias    = (const float*)d_in[7];
    const float* dw      = (const float*)d_in[8];
    const float* db      = (const float*)d_in[9];
    float* out = (float*)d_out;

    gru_fused<<<dim3(BQ), dim3(128), 0, stream>>>(
        values, lengths, Wk, Wr, bias, dw, db, out);
}